// Round 9
// baseline (595.061 us; speedup 1.0000x reference)
//
#include <hip/hip_runtime.h>

#define N_NODES 100000
#define N_EDGES 1200000
#define CH 64
#define NG 256
#define OC 8
#define NBUK 196        // ceil(N_NODES/512)
#define BINCHUNK 4096
#define NBLKA 293       // ceil(N_EDGES/BINCHUNK)
#define NSTRIP 6250     // N_NODES/16 (exact)
#define SHU 400000      // uints per shard  (N_NODES * 4)
#define SHS 800000      // ushorts per shard (N_NODES * 8)

typedef unsigned short ushort_t;
typedef unsigned int uint_t;
typedef __attribute__((ext_vector_type(8))) short bf16x8;
typedef __attribute__((ext_vector_type(4))) float f32x4;

__device__ __forceinline__ ushort_t f2bf(float f) {  // RNE f32->bf16
  uint_t u = __float_as_uint(f);
  return (ushort_t)((u + 0x7FFFu + ((u >> 16) & 1u)) >> 16);
}
__device__ __forceinline__ float bfE(uint_t u) {  // even channel (low 16)
  return __uint_as_float(u << 16);
}
__device__ __forceinline__ float bfO(uint_t u) {  // odd channel (high 16)
  return __uint_as_float(u & 0xFFFF0000u);
}

// ---------------- pass A1: per-bucket totals (dst>>9) ----------------
__global__ __launch_bounds__(256) void countA_k(const int* __restrict__ dst,
                                                int* __restrict__ gbase) {
  __shared__ int hist[NBUK];
  for (int i = threadIdx.x; i < NBUK; i += 256) hist[i] = 0;
  __syncthreads();
  const int cs = blockIdx.x * BINCHUNK;
  int ce = cs + BINCHUNK;
  if (ce > N_EDGES) ce = N_EDGES;
  for (int e = cs + threadIdx.x; e < ce; e += 256)
    atomicAdd(&hist[dst[e] >> 9], 1);
  __syncthreads();
  for (int b = threadIdx.x; b < NBUK; b += 256) {
    int c = hist[b];
    if (c) atomicAdd(&gbase[b], c);
  }
}

// ---------------- pass B: exclusive scan -> boff; cursor = boff ----------------
__global__ void scanB_k(const int* __restrict__ gbase, int* __restrict__ boff,
                        int* __restrict__ cursor) {
  __shared__ int s[256];
  int v = (threadIdx.x < NBUK) ? gbase[threadIdx.x] : 0;
  s[threadIdx.x] = v;
  __syncthreads();
  for (int o = 1; o < 256; o <<= 1) {
    int t = (threadIdx.x >= o) ? s[threadIdx.x - o] : 0;
    __syncthreads();
    s[threadIdx.x] += t;
    __syncthreads();
  }
  if (threadIdx.x < NBUK) {
    int ex = s[threadIdx.x] - v;
    boff[threadIdx.x] = ex;
    cursor[threadIdx.x] = ex;
  }
  if (threadIdx.x == NBUK - 1) boff[NBUK] = s[threadIdx.x];
}

// ---------------- pass A2: scatter packed edges into bucket regions ----------------
__global__ __launch_bounds__(256) void scatterA_k(const int* __restrict__ src,
                                                  const int* __restrict__ dst,
                                                  int* __restrict__ cursor,
                                                  int* __restrict__ tmp) {
  __shared__ int hist[NBUK];
  for (int i = threadIdx.x; i < NBUK; i += 256) hist[i] = 0;
  __syncthreads();
  const int cs = blockIdx.x * BINCHUNK;
  int ce = cs + BINCHUNK;
  if (ce > N_EDGES) ce = N_EDGES;
  for (int e = cs + threadIdx.x; e < ce; e += 256)
    atomicAdd(&hist[dst[e] >> 9], 1);
  __syncthreads();
  for (int b = threadIdx.x; b < NBUK; b += 256) {
    int c = hist[b];
    hist[b] = c ? atomicAdd(&cursor[b], c) : 0;
  }
  __syncthreads();
  for (int e = cs + threadIdx.x; e < ce; e += 256) {
    int d = dst[e];
    int slot = atomicAdd(&hist[d >> 9], 1);
    tmp[slot] = (src[e] << 9) | (d & 511);
  }
}

// ---------------- pass C: per-bucket fine CSR (rowptr + col) ----------------
__global__ __launch_bounds__(512) void csrC_k(const int* __restrict__ tmp,
                                              const int* __restrict__ boff,
                                              int* __restrict__ rp,
                                              int* __restrict__ col) {
  __shared__ int lh[512];
  __shared__ int s[512];
  const int b = blockIdx.x;
  const int tid = threadIdx.x;
  const int eb = boff[b], ee = boff[b + 1];
  lh[tid] = 0;
  __syncthreads();
  for (int e = eb + tid; e < ee; e += 512) atomicAdd(&lh[tmp[e] & 511], 1);
  __syncthreads();
  int v = lh[tid];
  s[tid] = v;
  __syncthreads();
  for (int o = 1; o < 512; o <<= 1) {
    int t = (tid >= o) ? s[tid - o] : 0;
    __syncthreads();
    s[tid] += t;
    __syncthreads();
  }
  const int base = eb + s[tid] - v;
  const int node = b * 512 + tid;
  if (node < N_NODES) rp[node] = base;
  if (b == 0 && tid == 0) rp[N_NODES] = N_EDGES;
  lh[tid] = base;
  __syncthreads();
  for (int e = eb + tid; e < ee; e += 512) {
    int p = tmp[e];
    int slot = atomicAdd(&lh[p & 511], 1);
    col[slot] = p >> 9;
  }
}

// ---------------- MFMA dual transform -> SHARDED bf16 outputs ----------------
// outl/outr layout: shard s (=ch>>3) is [N_NODES][8ch] contiguous bf16.
// One wave per 16-node strip. TIN = float (layer 1, dense rows) or
// ushort_t (layer 2, SHARDED input: shard kb at node = 16B A-fragment).
// A-row / B-col bound to lane&15; same k-grouping A/B (perm-safe).
// C/D mapping: col=lane&15, row=(lane>>4)*4+reg  [m89-verified].
template <typename TIN>
__global__ __launch_bounds__(256) void transform_mfma_k(
    const TIN* __restrict__ in, const float* __restrict__ Wl,
    const float* __restrict__ Wr, ushort_t* __restrict__ outl,
    ushort_t* __restrict__ outr) {
  const int wid = blockIdx.x * 4 + (threadIdx.x >> 6);
  if (wid >= NSTRIP) return;
  const int lane = threadIdx.x & 63;
  const int row = lane & 15;
  const int kb = lane >> 4;  // k-block 0..3 (8 contiguous k each)

  bf16x8 Bfrag[8][2];
#pragma unroll
  for (int t = 0; t < 8; ++t) {
    const float* W = (t < 4) ? Wl : Wr;
    const int j = (t & 3) * 16 + row;  // output channel = W row
#pragma unroll
    for (int h = 0; h < 2; ++h) {
      const float* p = W + j * CH + h * 32 + kb * 8;
      float4 w0 = *(const float4*)p;
      float4 w1 = *(const float4*)(p + 4);
      bf16x8 b;
      b[0] = (short)f2bf(w0.x); b[1] = (short)f2bf(w0.y);
      b[2] = (short)f2bf(w0.z); b[3] = (short)f2bf(w0.w);
      b[4] = (short)f2bf(w1.x); b[5] = (short)f2bf(w1.y);
      b[6] = (short)f2bf(w1.z); b[7] = (short)f2bf(w1.w);
      Bfrag[t][h] = b;
    }
  }

  const int n0 = wid * 16;
  bf16x8 Afrag[2];
#pragma unroll
  for (int h = 0; h < 2; ++h) {
    if constexpr (sizeof(TIN) == 4) {
      const float* p = (const float*)in + (size_t)(n0 + row) * CH + h * 32 + kb * 8;
      float4 a0 = *(const float4*)p;
      float4 a1 = *(const float4*)(p + 4);
      bf16x8 a;
      a[0] = (short)f2bf(a0.x); a[1] = (short)f2bf(a0.y);
      a[2] = (short)f2bf(a0.z); a[3] = (short)f2bf(a0.w);
      a[4] = (short)f2bf(a1.x); a[5] = (short)f2bf(a1.y);
      a[6] = (short)f2bf(a1.z); a[7] = (short)f2bf(a1.w);
      Afrag[h] = a;
    } else {
      // sharded bf16 input: shard (h*4+kb), node n0+row -> contiguous 16B
      const ushort_t* p =
          (const ushort_t*)in + (size_t)(h * 4 + kb) * SHS + (size_t)(n0 + row) * 8;
      Afrag[h] = *(const bf16x8*)p;
    }
  }

  f32x4 acc[8];
#pragma unroll
  for (int t = 0; t < 8; ++t) {
    acc[t] = (f32x4){0.f, 0.f, 0.f, 0.f};
    acc[t] = __builtin_amdgcn_mfma_f32_16x16x32_bf16(Afrag[0], Bfrag[t][0],
                                                     acc[t], 0, 0, 0);
    acc[t] = __builtin_amdgcn_mfma_f32_16x16x32_bf16(Afrag[1], Bfrag[t][1],
                                                     acc[t], 0, 0, 0);
  }

  const int orow = (lane >> 4) * 4;
#pragma unroll
  for (int t = 0; t < 4; ++t) {
    const int ch = t * 16 + row;
    ushort_t* po = outl + (size_t)(ch >> 3) * SHS + (ch & 7);
#pragma unroll
    for (int i = 0; i < 4; ++i)
      po[(size_t)(n0 + orow + i) * 8] = f2bf(acc[t][i]);
  }
#pragma unroll
  for (int t = 4; t < 8; ++t) {
    const int ch = (t - 4) * 16 + row;
    ushort_t* po = outr + (size_t)(ch >> 3) * SHS + (ch & 7);
#pragma unroll
    for (int i = 0; i < 4; ++i)
      po[(size_t)(n0 + orow + i) * 8] = f2bf(acc[t][i]);
  }
}

// ---------------- XCD-affine sharded gather + mean + bias + relu (+ pool) ----
// slice s = blockIdx&7 (default dispatch round-robins blockIdx across the 8
// XCDs -> all slice-s blocks share XCD s, whose L2 caches the 1.6MB shard).
// Wave per node: 64 lanes = 16 edges x 4 dwords (16B granule per edge).
template <int MODE>
__global__ __launch_bounds__(256) void gather_k(
    const uint_t* __restrict__ glu, const uint_t* __restrict__ gru,
    const float* __restrict__ bl, const int* __restrict__ rowptr,
    const int* __restrict__ col, uint_t* __restrict__ outu,
    const int* __restrict__ batch, float* __restrict__ gsum,
    int* __restrict__ gcnt) {
  const int s = blockIdx.x & 7;
  const uint_t* gls = glu + (size_t)s * SHU;
  const uint_t* grs = gru + (size_t)s * SHU;
  const int lane = threadIdx.x & 63;
  const int d = lane & 3;    // dword in 16B granule (2 channels)
  const int eg = lane >> 2;  // edge slot 0..15
  const float bE = bl[s * 8 + 2 * d];
  const float bO = bl[s * 8 + 2 * d + 1];
  const int chunk = (blockIdx.x >> 3) * 4 + (threadIdx.x >> 6);
  const int per = 196;  // 512 chunks * 196 >= N_NODES
  int ns = chunk * per;
  int ne = ns + per;
  if (ne > N_NODES) ne = N_NODES;
  if (ns >= ne) return;

  int curg = -1;
  float paccE = 0.f, paccO = 0.f;
  int pcnt = 0;
  int eb = rowptr[ns];

  for (int n = ns; n < ne; ++n) {
    const int ee = rowptr[n + 1];
    const int deg = ee - eb;
    float aE = 0.f, aO = 0.f;
    for (int g0 = eb; g0 < ee; g0 += 16) {
      int eidx = g0 + eg;
      if (eidx < ee) {
        int c = col[eidx];
        uint_t v = gls[(size_t)c * 4 + d];
        aE += bfE(v);
        aO += bfO(v);
      }
    }
#pragma unroll
    for (int o = 4; o <= 32; o <<= 1) {
      aE += __shfl_xor(aE, o);
      aO += __shfl_xor(aO, o);
    }
    const float inv = deg > 0 ? 1.f / (float)deg : 1.f;
    const uint_t ug = grs[(size_t)n * 4 + d];
    const float rE = fmaxf(fmaf(aE, inv, bE + bfE(ug)), 0.f);
    const float rO = fmaxf(fmaf(aO, inv, bO + bfO(ug)), 0.f);
    if (MODE == 0) {
      if (lane < 4)
        outu[(size_t)s * SHU + (size_t)n * 4 + d] =
            ((uint_t)f2bf(rO) << 16) | f2bf(rE);
    } else {
      int g = batch[n];
      if (g != curg) {
        if (curg >= 0) {
          if (lane < 4) {
            atomicAdd(&gsum[curg * CH + s * 8 + 2 * d], paccE);
            atomicAdd(&gsum[curg * CH + s * 8 + 2 * d + 1], paccO);
          }
          if (s == 0 && lane == 0) atomicAdd(&gcnt[curg], pcnt);
        }
        curg = g;
        paccE = 0.f;
        paccO = 0.f;
        pcnt = 0;
      }
      paccE += rE;
      paccO += rO;
      pcnt++;
    }
    eb = ee;
  }
  if (MODE == 1 && curg >= 0) {
    if (lane < 4) {
      atomicAdd(&gsum[curg * CH + s * 8 + 2 * d], paccE);
      atomicAdd(&gsum[curg * CH + s * 8 + 2 * d + 1], paccO);
    }
    if (s == 0 && lane == 0) atomicAdd(&gcnt[curg], pcnt);
  }
}

// ---------------- final projection ----------------
__global__ void final_k(const float* __restrict__ gsum, const int* __restrict__ gcnt,
                        const float* __restrict__ Wc, const float* __restrict__ bc,
                        float* __restrict__ out) {
  __shared__ float Wcs[OC * CH];
  __shared__ float bcs[OC];
  for (int i = threadIdx.x; i < OC * CH; i += blockDim.x) Wcs[i] = Wc[i];
  if (threadIdx.x < OC) bcs[threadIdx.x] = bc[threadIdx.x];
  __syncthreads();
  int g = threadIdx.x;
  float c = (float)gcnt[g];
  float inv = c > 0.f ? 1.f / c : 1.f;
  float gr[CH];
#pragma unroll
  for (int k = 0; k < CH; ++k) gr[k] = gsum[g * CH + k] * inv;
#pragma unroll
  for (int o = 0; o < OC; ++o) {
    float acc = bcs[o];
#pragma unroll
    for (int k = 0; k < CH; ++k) acc += gr[k] * Wcs[o * CH + k];
    out[g * OC + o] = acc;
  }
}

extern "C" void kernel_launch(void* const* d_in, const int* in_sizes, int n_in,
                              void* d_out, int out_size, void* d_ws, size_t ws_size,
                              hipStream_t stream) {
  const float* x   = (const float*)d_in[0];
  const int*   ei  = (const int*)d_in[1];
  const int*   bat = (const int*)d_in[2];
  const float* W1l = (const float*)d_in[3];
  const float* b1l = (const float*)d_in[4];
  const float* W1r = (const float*)d_in[5];
  const float* W2l = (const float*)d_in[6];
  const float* b2l = (const float*)d_in[7];
  const float* W2r = (const float*)d_in[8];
  const float* Wc  = (const float*)d_in[9];
  const float* bc  = (const float*)d_in[10];
  float* out = (float*)d_out;

  char* ws = (char*)d_ws;
  // sharded bf16 buffers, 12.8MB each (8 shards x 1.6MB):
  //   buf1: xl -> h2l     buf3: h1     buf2: xr -> h2r
  ushort_t* buf1 = (ushort_t*)(ws + 0);         // 12,800,000 B
  ushort_t* buf3 = (ushort_t*)(ws + 12800000);  // 12,800,000 B
  ushort_t* buf2 = (ushort_t*)(ws + 25600000);  // 12,800,000 B
  int*   tmp     = (int*)(ws + 0);              //  4,800,000 B (aliased w/ buf1; CSR phase only)
  int*   rp      = (int*)(ws + 51200000);       //    400,128 B (incl pad)
  int*   col     = (int*)(ws + 51600128);       //  4,800,000 B
  int*   gbase   = (int*)(ws + 56400128);       //      1,024 B
  int*   boff    = (int*)(ws + 56401152);       //      1,024 B
  int*   cursor  = (int*)(ws + 56402176);       //      1,024 B
  float* gsum    = (float*)(ws + 56403200);     //     65,536 B
  int*   gcnt    = (int*)(ws + 56468736);       //      1,024 B

  const int* src = ei;
  const int* dst = ei + N_EDGES;

  hipMemsetAsync(gbase, 0, NBUK * sizeof(int), stream);
  hipMemsetAsync(gsum, 0, (size_t)NG * CH * sizeof(float) + NG * sizeof(int), stream);

  // ---- CSR build (bucketed counting sort) ----
  countA_k<<<NBLKA, 256, 0, stream>>>(dst, gbase);
  scanB_k<<<1, 256, 0, stream>>>(gbase, boff, cursor);
  scatterA_k<<<NBLKA, 256, 0, stream>>>(src, dst, cursor, tmp);
  csrC_k<<<NBUK, 512, 0, stream>>>(tmp, boff, rp, col);

  // ---- layer 1: x(f32) -> xl(buf1,sharded), xr(buf2,sharded); gather -> h1(buf3) ----
  transform_mfma_k<float><<<(NSTRIP + 3) / 4, 256, 0, stream>>>(x, W1l, W1r,
                                                                buf1, buf2);
  gather_k<0><<<1024, 256, 0, stream>>>((const uint_t*)buf1, (const uint_t*)buf2,
                                        b1l, rp, col, (uint_t*)buf3,
                                        nullptr, nullptr, nullptr);
  // ---- layer 2: h1(buf3,sharded) -> h2l(buf1), h2r(buf2); gather+pool ----
  transform_mfma_k<ushort_t><<<(NSTRIP + 3) / 4, 256, 0, stream>>>(buf3, W2l, W2r,
                                                                   buf1, buf2);
  gather_k<1><<<1024, 256, 0, stream>>>((const uint_t*)buf1, (const uint_t*)buf2,
                                        b2l, rp, col, nullptr,
                                        bat, gsum, gcnt);
  // ---- classify ----
  final_k<<<1, 256, 0, stream>>>(gsum, gcnt, Wc, bc, out);
}

// Round 10
// 417.726 us; speedup vs baseline: 1.4245x; 1.4245x over previous
//
#include <hip/hip_runtime.h>

#define N_NODES 100000
#define N_EDGES 1200000
#define CH 64
#define NG 256
#define OC 8
#define NBUK 196        // ceil(N_NODES/512)
#define BINCHUNK 4096
#define NBLKA 293       // ceil(N_EDGES/BINCHUNK)
#define NSTRIP 6250     // N_NODES/16 (exact)
#define SHU 400000      // uints per shard  (N_NODES * 4)
#define SHS 800000      // ushorts per shard (N_NODES * 8)
#define NPG 7           // nodes per 4-lane group (16384 groups/slice * 7 >= N)

typedef unsigned short ushort_t;
typedef unsigned int uint_t;
typedef __attribute__((ext_vector_type(8))) short bf16x8;
typedef __attribute__((ext_vector_type(4))) float f32x4;

__device__ __forceinline__ ushort_t f2bf(float f) {  // RNE f32->bf16
  uint_t u = __float_as_uint(f);
  return (ushort_t)((u + 0x7FFFu + ((u >> 16) & 1u)) >> 16);
}
__device__ __forceinline__ float bfE(uint_t u) {  // even channel (low 16)
  return __uint_as_float(u << 16);
}
__device__ __forceinline__ float bfO(uint_t u) {  // odd channel (high 16)
  return __uint_as_float(u & 0xFFFF0000u);
}

// ---------------- pass A1: per-bucket totals (dst>>9) ----------------
__global__ __launch_bounds__(256) void countA_k(const int* __restrict__ dst,
                                                int* __restrict__ gbase) {
  __shared__ int hist[NBUK];
  for (int i = threadIdx.x; i < NBUK; i += 256) hist[i] = 0;
  __syncthreads();
  const int cs = blockIdx.x * BINCHUNK;
  int ce = cs + BINCHUNK;
  if (ce > N_EDGES) ce = N_EDGES;
  for (int e = cs + threadIdx.x; e < ce; e += 256)
    atomicAdd(&hist[dst[e] >> 9], 1);
  __syncthreads();
  for (int b = threadIdx.x; b < NBUK; b += 256) {
    int c = hist[b];
    if (c) atomicAdd(&gbase[b], c);
  }
}

// ---------------- pass B: exclusive scan -> boff; cursor = boff ----------------
__global__ void scanB_k(const int* __restrict__ gbase, int* __restrict__ boff,
                        int* __restrict__ cursor) {
  __shared__ int s[256];
  int v = (threadIdx.x < NBUK) ? gbase[threadIdx.x] : 0;
  s[threadIdx.x] = v;
  __syncthreads();
  for (int o = 1; o < 256; o <<= 1) {
    int t = (threadIdx.x >= o) ? s[threadIdx.x - o] : 0;
    __syncthreads();
    s[threadIdx.x] += t;
    __syncthreads();
  }
  if (threadIdx.x < NBUK) {
    int ex = s[threadIdx.x] - v;
    boff[threadIdx.x] = ex;
    cursor[threadIdx.x] = ex;
  }
  if (threadIdx.x == NBUK - 1) boff[NBUK] = s[threadIdx.x];
}

// ---------------- pass A2: scatter packed edges into bucket regions ----------------
__global__ __launch_bounds__(256) void scatterA_k(const int* __restrict__ src,
                                                  const int* __restrict__ dst,
                                                  int* __restrict__ cursor,
                                                  int* __restrict__ tmp) {
  __shared__ int hist[NBUK];
  for (int i = threadIdx.x; i < NBUK; i += 256) hist[i] = 0;
  __syncthreads();
  const int cs = blockIdx.x * BINCHUNK;
  int ce = cs + BINCHUNK;
  if (ce > N_EDGES) ce = N_EDGES;
  for (int e = cs + threadIdx.x; e < ce; e += 256)
    atomicAdd(&hist[dst[e] >> 9], 1);
  __syncthreads();
  for (int b = threadIdx.x; b < NBUK; b += 256) {
    int c = hist[b];
    hist[b] = c ? atomicAdd(&cursor[b], c) : 0;
  }
  __syncthreads();
  for (int e = cs + threadIdx.x; e < ce; e += 256) {
    int d = dst[e];
    int slot = atomicAdd(&hist[d >> 9], 1);
    tmp[slot] = (src[e] << 9) | (d & 511);
  }
}

// ---------------- pass C: per-bucket fine CSR (rowptr + col) ----------------
__global__ __launch_bounds__(512) void csrC_k(const int* __restrict__ tmp,
                                              const int* __restrict__ boff,
                                              int* __restrict__ rp,
                                              int* __restrict__ col) {
  __shared__ int lh[512];
  __shared__ int s[512];
  const int b = blockIdx.x;
  const int tid = threadIdx.x;
  const int eb = boff[b], ee = boff[b + 1];
  lh[tid] = 0;
  __syncthreads();
  for (int e = eb + tid; e < ee; e += 512) atomicAdd(&lh[tmp[e] & 511], 1);
  __syncthreads();
  int v = lh[tid];
  s[tid] = v;
  __syncthreads();
  for (int o = 1; o < 512; o <<= 1) {
    int t = (tid >= o) ? s[tid - o] : 0;
    __syncthreads();
    s[tid] += t;
    __syncthreads();
  }
  const int base = eb + s[tid] - v;
  const int node = b * 512 + tid;
  if (node < N_NODES) rp[node] = base;
  if (b == 0 && tid == 0) rp[N_NODES] = N_EDGES;
  lh[tid] = base;
  __syncthreads();
  for (int e = eb + tid; e < ee; e += 512) {
    int p = tmp[e];
    int slot = atomicAdd(&lh[p & 511], 1);
    col[slot] = p >> 9;
  }
}

// ---------------- MFMA dual transform -> SHARDED bf16 outputs ----------------
// outl/outr layout: shard s (=ch>>3) is [N_NODES][8ch] contiguous bf16.
// One wave per 16-node strip. TIN = float (layer 1, dense rows) or
// ushort_t (layer 2, SHARDED input: shard kb at node = 16B A-fragment).
// C/D mapping: col=lane&15, row=(lane>>4)*4+reg  [m89-verified].
template <typename TIN>
__global__ __launch_bounds__(256) void transform_mfma_k(
    const TIN* __restrict__ in, const float* __restrict__ Wl,
    const float* __restrict__ Wr, ushort_t* __restrict__ outl,
    ushort_t* __restrict__ outr) {
  const int wid = blockIdx.x * 4 + (threadIdx.x >> 6);
  if (wid >= NSTRIP) return;
  const int lane = threadIdx.x & 63;
  const int row = lane & 15;
  const int kb = lane >> 4;  // k-block 0..3 (8 contiguous k each)

  bf16x8 Bfrag[8][2];
#pragma unroll
  for (int t = 0; t < 8; ++t) {
    const float* W = (t < 4) ? Wl : Wr;
    const int j = (t & 3) * 16 + row;  // output channel = W row
#pragma unroll
    for (int h = 0; h < 2; ++h) {
      const float* p = W + j * CH + h * 32 + kb * 8;
      float4 w0 = *(const float4*)p;
      float4 w1 = *(const float4*)(p + 4);
      bf16x8 b;
      b[0] = (short)f2bf(w0.x); b[1] = (short)f2bf(w0.y);
      b[2] = (short)f2bf(w0.z); b[3] = (short)f2bf(w0.w);
      b[4] = (short)f2bf(w1.x); b[5] = (short)f2bf(w1.y);
      b[6] = (short)f2bf(w1.z); b[7] = (short)f2bf(w1.w);
      Bfrag[t][h] = b;
    }
  }

  const int n0 = wid * 16;
  bf16x8 Afrag[2];
#pragma unroll
  for (int h = 0; h < 2; ++h) {
    if constexpr (sizeof(TIN) == 4) {
      const float* p = (const float*)in + (size_t)(n0 + row) * CH + h * 32 + kb * 8;
      float4 a0 = *(const float4*)p;
      float4 a1 = *(const float4*)(p + 4);
      bf16x8 a;
      a[0] = (short)f2bf(a0.x); a[1] = (short)f2bf(a0.y);
      a[2] = (short)f2bf(a0.z); a[3] = (short)f2bf(a0.w);
      a[4] = (short)f2bf(a1.x); a[5] = (short)f2bf(a1.y);
      a[6] = (short)f2bf(a1.z); a[7] = (short)f2bf(a1.w);
      Afrag[h] = a;
    } else {
      // sharded bf16 input: shard (h*4+kb), node n0+row -> contiguous 16B
      const ushort_t* p =
          (const ushort_t*)in + (size_t)(h * 4 + kb) * SHS + (size_t)(n0 + row) * 8;
      Afrag[h] = *(const bf16x8*)p;
    }
  }

  f32x4 acc[8];
#pragma unroll
  for (int t = 0; t < 8; ++t) {
    acc[t] = (f32x4){0.f, 0.f, 0.f, 0.f};
    acc[t] = __builtin_amdgcn_mfma_f32_16x16x32_bf16(Afrag[0], Bfrag[t][0],
                                                     acc[t], 0, 0, 0);
    acc[t] = __builtin_amdgcn_mfma_f32_16x16x32_bf16(Afrag[1], Bfrag[t][1],
                                                     acc[t], 0, 0, 0);
  }

  const int orow = (lane >> 4) * 4;
#pragma unroll
  for (int t = 0; t < 4; ++t) {
    const int ch = t * 16 + row;
    ushort_t* po = outl + (size_t)(ch >> 3) * SHS + (ch & 7);
#pragma unroll
    for (int i = 0; i < 4; ++i)
      po[(size_t)(n0 + orow + i) * 8] = f2bf(acc[t][i]);
  }
#pragma unroll
  for (int t = 4; t < 8; ++t) {
    const int ch = (t - 4) * 16 + row;
    ushort_t* po = outr + (size_t)(ch >> 3) * SHS + (ch & 7);
#pragma unroll
    for (int i = 0; i < 4; ++i)
      po[(size_t)(n0 + orow + i) * 8] = f2bf(acc[t][i]);
  }
}

// ---------------- XCD-affine sharded gather, 4-lane groups, flat edge walk ----
// slice s = blockIdx&7 -> all slice-s blocks land on XCD s; shard (1.6MB) is
// L2-resident there. Group of 4 lanes owns one node range; lane d owns dword
// d (2 channels) of the 16B shard row -> no cross-lane reduction at all.
// Flat edge loop with finalize-on-boundary: wave slack = max over groups of
// SUM of degrees (~+25%), not per-node max.
template <int MODE>
__global__ __launch_bounds__(256) void gather_k(
    const uint_t* __restrict__ glu, const uint_t* __restrict__ gru,
    const float* __restrict__ bl, const int* __restrict__ rowptr,
    const int* __restrict__ col, uint_t* __restrict__ outu,
    const int* __restrict__ batch, float* __restrict__ gsum,
    int* __restrict__ gcnt) {
  const int s = blockIdx.x & 7;
  const uint_t* gls = glu + (size_t)s * SHU;
  const uint_t* grs = gru + (size_t)s * SHU;
  const int lane = threadIdx.x & 63;
  const int d = lane & 3;  // dword within 16B shard row (2 channels)
  const float bE = bl[s * 8 + 2 * d];
  const float bO = bl[s * 8 + 2 * d + 1];
  // group id within slice: 1024 waves/slice * 16 groups = 16384 groups
  const int wslice = (blockIdx.x >> 3) * 4 + (threadIdx.x >> 6);
  const int gid = wslice * 16 + (lane >> 2);
  int ns = gid * NPG;
  int ne = ns + NPG;
  if (ne > N_NODES) ne = N_NODES;
  if (ns >= N_NODES) return;

  int e = rowptr[ns];
  const int eend = rowptr[ne];
  int n = ns;
  int nst = e;
  int nb = rowptr[ns + 1];
  float aE = 0.f, aO = 0.f;
  int curg = -1;
  float paccE = 0.f, paccO = 0.f;
  int pcnt = 0;

  for (;;) {
    // finalize every node whose edge range is exhausted (zero-degree safe)
    while (n < ne && e == nb) {
      const int deg = nb - nst;
      const float inv = deg > 0 ? 1.f / (float)deg : 1.f;
      const uint_t ug = grs[(size_t)n * 4 + d];
      const float rE = fmaxf(fmaf(aE, inv, bE + bfE(ug)), 0.f);
      const float rO = fmaxf(fmaf(aO, inv, bO + bfO(ug)), 0.f);
      if (MODE == 0) {
        outu[(size_t)s * SHU + (size_t)n * 4 + d] =
            ((uint_t)f2bf(rO) << 16) | (uint_t)f2bf(rE);
      } else {
        const int g = batch[n];
        if (g != curg) {
          if (curg >= 0) {
            atomicAdd(&gsum[curg * CH + s * 8 + 2 * d], paccE);
            atomicAdd(&gsum[curg * CH + s * 8 + 2 * d + 1], paccO);
            if (s == 0 && d == 0) atomicAdd(&gcnt[curg], pcnt);
          }
          curg = g;
          paccE = 0.f;
          paccO = 0.f;
          pcnt = 0;
        }
        paccE += rE;
        paccO += rO;
        ++pcnt;
      }
      aE = 0.f;
      aO = 0.f;
      ++n;
      nst = nb;
      if (n < ne) nb = rowptr[n + 1];
    }
    if (e >= eend) break;
    const int c = col[e];
    const uint_t v = gls[(size_t)c * 4 + d];
    aE += bfE(v);
    aO += bfO(v);
    ++e;
  }
  if (MODE == 1 && curg >= 0) {
    atomicAdd(&gsum[curg * CH + s * 8 + 2 * d], paccE);
    atomicAdd(&gsum[curg * CH + s * 8 + 2 * d + 1], paccO);
    if (s == 0 && d == 0) atomicAdd(&gcnt[curg], pcnt);
  }
}

// ---------------- final projection ----------------
__global__ void final_k(const float* __restrict__ gsum, const int* __restrict__ gcnt,
                        const float* __restrict__ Wc, const float* __restrict__ bc,
                        float* __restrict__ out) {
  __shared__ float Wcs[OC * CH];
  __shared__ float bcs[OC];
  for (int i = threadIdx.x; i < OC * CH; i += blockDim.x) Wcs[i] = Wc[i];
  if (threadIdx.x < OC) bcs[threadIdx.x] = bc[threadIdx.x];
  __syncthreads();
  int g = threadIdx.x;
  float c = (float)gcnt[g];
  float inv = c > 0.f ? 1.f / c : 1.f;
  float gr[CH];
#pragma unroll
  for (int k = 0; k < CH; ++k) gr[k] = gsum[g * CH + k] * inv;
#pragma unroll
  for (int o = 0; o < OC; ++o) {
    float acc = bcs[o];
#pragma unroll
    for (int k = 0; k < CH; ++k) acc += gr[k] * Wcs[o * CH + k];
    out[g * OC + o] = acc;
  }
}

extern "C" void kernel_launch(void* const* d_in, const int* in_sizes, int n_in,
                              void* d_out, int out_size, void* d_ws, size_t ws_size,
                              hipStream_t stream) {
  const float* x   = (const float*)d_in[0];
  const int*   ei  = (const int*)d_in[1];
  const int*   bat = (const int*)d_in[2];
  const float* W1l = (const float*)d_in[3];
  const float* b1l = (const float*)d_in[4];
  const float* W1r = (const float*)d_in[5];
  const float* W2l = (const float*)d_in[6];
  const float* b2l = (const float*)d_in[7];
  const float* W2r = (const float*)d_in[8];
  const float* Wc  = (const float*)d_in[9];
  const float* bc  = (const float*)d_in[10];
  float* out = (float*)d_out;

  char* ws = (char*)d_ws;
  // sharded bf16 buffers, 12.8MB each (8 shards x 1.6MB):
  //   buf1: xl -> h2l     buf3: h1     buf2: xr -> h2r
  ushort_t* buf1 = (ushort_t*)(ws + 0);         // 12,800,000 B
  ushort_t* buf3 = (ushort_t*)(ws + 12800000);  // 12,800,000 B
  ushort_t* buf2 = (ushort_t*)(ws + 25600000);  // 12,800,000 B
  int*   tmp     = (int*)(ws + 0);              //  4,800,000 B (aliased w/ buf1; CSR phase only)
  int*   rp      = (int*)(ws + 51200000);       //    400,128 B (incl pad)
  int*   col     = (int*)(ws + 51600128);       //  4,800,000 B
  int*   gbase   = (int*)(ws + 56400128);       //      1,024 B
  int*   boff    = (int*)(ws + 56401152);       //      1,024 B
  int*   cursor  = (int*)(ws + 56402176);       //      1,024 B
  float* gsum    = (float*)(ws + 56403200);     //     65,536 B
  int*   gcnt    = (int*)(ws + 56468736);       //      1,024 B

  const int* src = ei;
  const int* dst = ei + N_EDGES;

  hipMemsetAsync(gbase, 0, NBUK * sizeof(int), stream);
  hipMemsetAsync(gsum, 0, (size_t)NG * CH * sizeof(float) + NG * sizeof(int), stream);

  // ---- CSR build (bucketed counting sort) ----
  countA_k<<<NBLKA, 256, 0, stream>>>(dst, gbase);
  scanB_k<<<1, 256, 0, stream>>>(gbase, boff, cursor);
  scatterA_k<<<NBLKA, 256, 0, stream>>>(src, dst, cursor, tmp);
  csrC_k<<<NBUK, 512, 0, stream>>>(tmp, boff, rp, col);

  // ---- layer 1: x(f32) -> xl(buf1,sharded), xr(buf2,sharded); gather -> h1(buf3) ----
  transform_mfma_k<float><<<(NSTRIP + 3) / 4, 256, 0, stream>>>(x, W1l, W1r,
                                                                buf1, buf2);
  gather_k<0><<<2048, 256, 0, stream>>>((const uint_t*)buf1, (const uint_t*)buf2,
                                        b1l, rp, col, (uint_t*)buf3,
                                        nullptr, nullptr, nullptr);
  // ---- layer 2: h1(buf3,sharded) -> h2l(buf1), h2r(buf2); gather+pool ----
  transform_mfma_k<ushort_t><<<(NSTRIP + 3) / 4, 256, 0, stream>>>(buf3, W2l, W2r,
                                                                   buf1, buf2);
  gather_k<1><<<2048, 256, 0, stream>>>((const uint_t*)buf1, (const uint_t*)buf2,
                                        b2l, rp, col, nullptr,
                                        bat, gsum, gcnt);
  // ---- classify ----
  final_k<<<1, 256, 0, stream>>>(gsum, gcnt, Wc, bc, out);
}

// Round 11
// 400.091 us; speedup vs baseline: 1.4873x; 1.0441x over previous
//
#include <hip/hip_runtime.h>

#define N_NODES 100000
#define N_EDGES 1200000
#define CH 64
#define NG 256
#define OC 8
#define NBUK 196        // ceil(N_NODES/512)
#define BINCHUNK 4096
#define NBLKA 293       // ceil(N_EDGES/BINCHUNK)
#define NSTRIP 6250     // N_NODES/16 (exact)
#define SHU 400000      // uints per shard  (N_NODES * 4)
#define SHS 800000      // ushorts per shard (N_NODES * 8)
#define NPG2 8          // nodes per 4-lane group per claim
#define CHNODES 512     // 64 groups * NPG2 nodes per block-claim
#define NCHUNK 196      // ceil(N_NODES / CHNODES)

typedef unsigned short ushort_t;
typedef unsigned int uint_t;
typedef __attribute__((ext_vector_type(8))) short bf16x8;
typedef __attribute__((ext_vector_type(4))) float f32x4;

__device__ __forceinline__ ushort_t f2bf(float f) {  // RNE f32->bf16
  uint_t u = __float_as_uint(f);
  return (ushort_t)((u + 0x7FFFu + ((u >> 16) & 1u)) >> 16);
}
__device__ __forceinline__ float bfE(uint_t u) {  // even channel (low 16)
  return __uint_as_float(u << 16);
}
__device__ __forceinline__ float bfO(uint_t u) {  // odd channel (high 16)
  return __uint_as_float(u & 0xFFFF0000u);
}

// ---------------- pass A1: per-bucket totals (dst>>9) ----------------
__global__ __launch_bounds__(256) void countA_k(const int* __restrict__ dst,
                                                int* __restrict__ gbase) {
  __shared__ int hist[NBUK];
  for (int i = threadIdx.x; i < NBUK; i += 256) hist[i] = 0;
  __syncthreads();
  const int cs = blockIdx.x * BINCHUNK;
  int ce = cs + BINCHUNK;
  if (ce > N_EDGES) ce = N_EDGES;
  for (int e = cs + threadIdx.x; e < ce; e += 256)
    atomicAdd(&hist[dst[e] >> 9], 1);
  __syncthreads();
  for (int b = threadIdx.x; b < NBUK; b += 256) {
    int c = hist[b];
    if (c) atomicAdd(&gbase[b], c);
  }
}

// ---------------- pass B: exclusive scan -> boff; cursor = boff ----------------
__global__ void scanB_k(const int* __restrict__ gbase, int* __restrict__ boff,
                        int* __restrict__ cursor) {
  __shared__ int s[256];
  int v = (threadIdx.x < NBUK) ? gbase[threadIdx.x] : 0;
  s[threadIdx.x] = v;
  __syncthreads();
  for (int o = 1; o < 256; o <<= 1) {
    int t = (threadIdx.x >= o) ? s[threadIdx.x - o] : 0;
    __syncthreads();
    s[threadIdx.x] += t;
    __syncthreads();
  }
  if (threadIdx.x < NBUK) {
    int ex = s[threadIdx.x] - v;
    boff[threadIdx.x] = ex;
    cursor[threadIdx.x] = ex;
  }
  if (threadIdx.x == NBUK - 1) boff[NBUK] = s[threadIdx.x];
}

// ---------------- pass A2: scatter packed edges into bucket regions ----------------
__global__ __launch_bounds__(256) void scatterA_k(const int* __restrict__ src,
                                                  const int* __restrict__ dst,
                                                  int* __restrict__ cursor,
                                                  int* __restrict__ tmp) {
  __shared__ int hist[NBUK];
  for (int i = threadIdx.x; i < NBUK; i += 256) hist[i] = 0;
  __syncthreads();
  const int cs = blockIdx.x * BINCHUNK;
  int ce = cs + BINCHUNK;
  if (ce > N_EDGES) ce = N_EDGES;
  for (int e = cs + threadIdx.x; e < ce; e += 256)
    atomicAdd(&hist[dst[e] >> 9], 1);
  __syncthreads();
  for (int b = threadIdx.x; b < NBUK; b += 256) {
    int c = hist[b];
    hist[b] = c ? atomicAdd(&cursor[b], c) : 0;
  }
  __syncthreads();
  for (int e = cs + threadIdx.x; e < ce; e += 256) {
    int d = dst[e];
    int slot = atomicAdd(&hist[d >> 9], 1);
    tmp[slot] = (src[e] << 9) | (d & 511);
  }
}

// ---------------- pass C: per-bucket fine CSR (rowptr + col) ----------------
__global__ __launch_bounds__(512) void csrC_k(const int* __restrict__ tmp,
                                              const int* __restrict__ boff,
                                              int* __restrict__ rp,
                                              int* __restrict__ col) {
  __shared__ int lh[512];
  __shared__ int s[512];
  const int b = blockIdx.x;
  const int tid = threadIdx.x;
  const int eb = boff[b], ee = boff[b + 1];
  lh[tid] = 0;
  __syncthreads();
  for (int e = eb + tid; e < ee; e += 512) atomicAdd(&lh[tmp[e] & 511], 1);
  __syncthreads();
  int v = lh[tid];
  s[tid] = v;
  __syncthreads();
  for (int o = 1; o < 512; o <<= 1) {
    int t = (tid >= o) ? s[tid - o] : 0;
    __syncthreads();
    s[tid] += t;
    __syncthreads();
  }
  const int base = eb + s[tid] - v;
  const int node = b * 512 + tid;
  if (node < N_NODES) rp[node] = base;
  if (b == 0 && tid == 0) rp[N_NODES] = N_EDGES;
  lh[tid] = base;
  __syncthreads();
  for (int e = eb + tid; e < ee; e += 512) {
    int p = tmp[e];
    int slot = atomicAdd(&lh[p & 511], 1);
    col[slot] = p >> 9;
  }
}

// ---------------- MFMA dual transform -> SHARDED bf16 outputs ----------------
// outl/outr layout: shard s (=ch>>3) is [N_NODES][8ch] contiguous bf16.
// C/D mapping: col=lane&15, row=(lane>>4)*4+reg  [m89-verified].
template <typename TIN>
__global__ __launch_bounds__(256) void transform_mfma_k(
    const TIN* __restrict__ in, const float* __restrict__ Wl,
    const float* __restrict__ Wr, ushort_t* __restrict__ outl,
    ushort_t* __restrict__ outr) {
  const int wid = blockIdx.x * 4 + (threadIdx.x >> 6);
  if (wid >= NSTRIP) return;
  const int lane = threadIdx.x & 63;
  const int row = lane & 15;
  const int kb = lane >> 4;  // k-block 0..3 (8 contiguous k each)

  bf16x8 Bfrag[8][2];
#pragma unroll
  for (int t = 0; t < 8; ++t) {
    const float* W = (t < 4) ? Wl : Wr;
    const int j = (t & 3) * 16 + row;  // output channel = W row
#pragma unroll
    for (int h = 0; h < 2; ++h) {
      const float* p = W + j * CH + h * 32 + kb * 8;
      float4 w0 = *(const float4*)p;
      float4 w1 = *(const float4*)(p + 4);
      bf16x8 b;
      b[0] = (short)f2bf(w0.x); b[1] = (short)f2bf(w0.y);
      b[2] = (short)f2bf(w0.z); b[3] = (short)f2bf(w0.w);
      b[4] = (short)f2bf(w1.x); b[5] = (short)f2bf(w1.y);
      b[6] = (short)f2bf(w1.z); b[7] = (short)f2bf(w1.w);
      Bfrag[t][h] = b;
    }
  }

  const int n0 = wid * 16;
  bf16x8 Afrag[2];
#pragma unroll
  for (int h = 0; h < 2; ++h) {
    if constexpr (sizeof(TIN) == 4) {
      const float* p = (const float*)in + (size_t)(n0 + row) * CH + h * 32 + kb * 8;
      float4 a0 = *(const float4*)p;
      float4 a1 = *(const float4*)(p + 4);
      bf16x8 a;
      a[0] = (short)f2bf(a0.x); a[1] = (short)f2bf(a0.y);
      a[2] = (short)f2bf(a0.z); a[3] = (short)f2bf(a0.w);
      a[4] = (short)f2bf(a1.x); a[5] = (short)f2bf(a1.y);
      a[6] = (short)f2bf(a1.z); a[7] = (short)f2bf(a1.w);
      Afrag[h] = a;
    } else {
      // sharded bf16 input: shard (h*4+kb), node n0+row -> contiguous 16B
      const ushort_t* p =
          (const ushort_t*)in + (size_t)(h * 4 + kb) * SHS + (size_t)(n0 + row) * 8;
      Afrag[h] = *(const bf16x8*)p;
    }
  }

  f32x4 acc[8];
#pragma unroll
  for (int t = 0; t < 8; ++t) {
    acc[t] = (f32x4){0.f, 0.f, 0.f, 0.f};
    acc[t] = __builtin_amdgcn_mfma_f32_16x16x32_bf16(Afrag[0], Bfrag[t][0],
                                                     acc[t], 0, 0, 0);
    acc[t] = __builtin_amdgcn_mfma_f32_16x16x32_bf16(Afrag[1], Bfrag[t][1],
                                                     acc[t], 0, 0, 0);
  }

  const int orow = (lane >> 4) * 4;
#pragma unroll
  for (int t = 0; t < 4; ++t) {
    const int ch = t * 16 + row;
    ushort_t* po = outl + (size_t)(ch >> 3) * SHS + (ch & 7);
#pragma unroll
    for (int i = 0; i < 4; ++i)
      po[(size_t)(n0 + orow + i) * 8] = f2bf(acc[t][i]);
  }
#pragma unroll
  for (int t = 4; t < 8; ++t) {
    const int ch = (t - 4) * 16 + row;
    ushort_t* po = outr + (size_t)(ch >> 3) * SHS + (ch & 7);
#pragma unroll
    for (int i = 0; i < 4; ++i)
      po[(size_t)(n0 + orow + i) * 8] = f2bf(acc[t][i]);
  }
}

// ---------------- XCD-verified sharded gather (persistent, self-scheduling) ----
// Each block reads its PHYSICAL XCD id (HW_REG_XCC_ID, m09) and claims
// 512-node chunks from its shard's cursor -> every random gls read targets
// the 1.6MB shard resident in THIS XCD's L2, regardless of dispatch mapping.
// 4-lane group per node; lane d owns dword d (2 channels) -> no reductions.
template <int MODE>
__global__ __launch_bounds__(256) void gather_k(
    const uint_t* __restrict__ glu, const uint_t* __restrict__ gru,
    const float* __restrict__ bl, const int* __restrict__ rowptr,
    const int* __restrict__ col, uint_t* __restrict__ outu,
    const int* __restrict__ batch, float* __restrict__ gsum,
    int* __restrict__ gcnt, int* __restrict__ cur) {
  __shared__ int sh_s;
  __shared__ int sh_c;
  if (threadIdx.x == 0) {
    uint_t xid;
    asm volatile("s_getreg_b32 %0, hwreg(HW_REG_XCC_ID)" : "=s"(xid));
    sh_s = (int)(xid & 7);
  }
  __syncthreads();
  const int s = sh_s;
  const uint_t* gls = glu + (size_t)s * SHU;
  const uint_t* grs = gru + (size_t)s * SHU;
  const int d = threadIdx.x & 3;     // dword within 16B shard row (2 channels)
  const int grp = threadIdx.x >> 2;  // group 0..63 in block
  const float bE = bl[s * 8 + 2 * d];
  const float bO = bl[s * 8 + 2 * d + 1];

  for (;;) {
    if (threadIdx.x == 0) sh_c = atomicAdd(&cur[s], 1);
    __syncthreads();
    const int c = sh_c;
    __syncthreads();
    if (c >= NCHUNK) break;  // uniform per block
    int ns = c * CHNODES + grp * NPG2;
    int ne = ns + NPG2;
    if (ne > N_NODES) ne = N_NODES;
    if (ns < ne) {
      int curg = -1;
      float paccE = 0.f, paccO = 0.f;
      int pcnt = 0;
      int eb = rowptr[ns];
      for (int n = ns; n < ne; ++n) {
        const int ee = rowptr[n + 1];
        float aE0 = 0.f, aO0 = 0.f, aE1 = 0.f, aO1 = 0.f;
        int e = eb;
        for (; e + 2 <= ee; e += 2) {
          const int c0 = col[e], c1 = col[e + 1];
          const uint_t v0 = gls[(size_t)c0 * 4 + d];
          const uint_t v1 = gls[(size_t)c1 * 4 + d];
          aE0 += bfE(v0); aO0 += bfO(v0);
          aE1 += bfE(v1); aO1 += bfO(v1);
        }
        if (e < ee) {
          const uint_t v = gls[(size_t)col[e] * 4 + d];
          aE0 += bfE(v); aO0 += bfO(v);
        }
        const int deg = ee - eb;
        const float inv = deg > 0 ? 1.f / (float)deg : 1.f;
        const uint_t ug = grs[(size_t)n * 4 + d];
        const float rE = fmaxf(fmaf(aE0 + aE1, inv, bE + bfE(ug)), 0.f);
        const float rO = fmaxf(fmaf(aO0 + aO1, inv, bO + bfO(ug)), 0.f);
        if (MODE == 0) {
          outu[(size_t)s * SHU + (size_t)n * 4 + d] =
              ((uint_t)f2bf(rO) << 16) | (uint_t)f2bf(rE);
        } else {
          const int g = batch[n];
          if (g != curg) {
            if (curg >= 0) {
              atomicAdd(&gsum[curg * CH + s * 8 + 2 * d], paccE);
              atomicAdd(&gsum[curg * CH + s * 8 + 2 * d + 1], paccO);
              if (s == 0 && d == 0) atomicAdd(&gcnt[curg], pcnt);
            }
            curg = g;
            paccE = 0.f;
            paccO = 0.f;
            pcnt = 0;
          }
          paccE += rE;
          paccO += rO;
          ++pcnt;
        }
        eb = ee;
      }
      if (MODE == 1 && curg >= 0) {
        atomicAdd(&gsum[curg * CH + s * 8 + 2 * d], paccE);
        atomicAdd(&gsum[curg * CH + s * 8 + 2 * d + 1], paccO);
        if (s == 0 && d == 0) atomicAdd(&gcnt[curg], pcnt);
      }
    }
  }
}

// ---------------- final projection ----------------
__global__ void final_k(const float* __restrict__ gsum, const int* __restrict__ gcnt,
                        const float* __restrict__ Wc, const float* __restrict__ bc,
                        float* __restrict__ out) {
  __shared__ float Wcs[OC * CH];
  __shared__ float bcs[OC];
  for (int i = threadIdx.x; i < OC * CH; i += blockDim.x) Wcs[i] = Wc[i];
  if (threadIdx.x < OC) bcs[threadIdx.x] = bc[threadIdx.x];
  __syncthreads();
  int g = threadIdx.x;
  float c = (float)gcnt[g];
  float inv = c > 0.f ? 1.f / c : 1.f;
  float gr[CH];
#pragma unroll
  for (int k = 0; k < CH; ++k) gr[k] = gsum[g * CH + k] * inv;
#pragma unroll
  for (int o = 0; o < OC; ++o) {
    float acc = bcs[o];
#pragma unroll
    for (int k = 0; k < CH; ++k) acc += gr[k] * Wcs[o * CH + k];
    out[g * OC + o] = acc;
  }
}

extern "C" void kernel_launch(void* const* d_in, const int* in_sizes, int n_in,
                              void* d_out, int out_size, void* d_ws, size_t ws_size,
                              hipStream_t stream) {
  const float* x   = (const float*)d_in[0];
  const int*   ei  = (const int*)d_in[1];
  const int*   bat = (const int*)d_in[2];
  const float* W1l = (const float*)d_in[3];
  const float* b1l = (const float*)d_in[4];
  const float* W1r = (const float*)d_in[5];
  const float* W2l = (const float*)d_in[6];
  const float* b2l = (const float*)d_in[7];
  const float* W2r = (const float*)d_in[8];
  const float* Wc  = (const float*)d_in[9];
  const float* bc  = (const float*)d_in[10];
  float* out = (float*)d_out;

  char* ws = (char*)d_ws;
  // sharded bf16 buffers, 12.8MB each (8 shards x 1.6MB):
  //   buf1: xl -> h2l     buf3: h1     buf2: xr -> h2r
  ushort_t* buf1 = (ushort_t*)(ws + 0);         // 12,800,000 B
  ushort_t* buf3 = (ushort_t*)(ws + 12800000);  // 12,800,000 B
  ushort_t* buf2 = (ushort_t*)(ws + 25600000);  // 12,800,000 B
  int*   tmp     = (int*)(ws + 0);              //  4,800,000 B (aliased w/ buf1; CSR phase only)
  int*   rp      = (int*)(ws + 51200000);       //    400,128 B (incl pad)
  int*   col     = (int*)(ws + 51600128);       //  4,800,000 B
  int*   gbase   = (int*)(ws + 56400128);       //      1,024 B
  int*   boff    = (int*)(ws + 56401152);       //      1,024 B
  int*   cursor  = (int*)(ws + 56402176);       //      1,024 B
  float* gsum    = (float*)(ws + 56403200);     //     65,536 B
  int*   gcnt    = (int*)(ws + 56468736);       //      1,024 B
  int*   cur1    = (int*)(ws + 56469760);       //         32 B
  int*   cur2    = (int*)(ws + 56469792);       //         32 B

  const int* src = ei;
  const int* dst = ei + N_EDGES;

  hipMemsetAsync(gbase, 0, NBUK * sizeof(int), stream);
  hipMemsetAsync(gsum, 0, (size_t)NG * CH * sizeof(float) + NG * sizeof(int), stream);
  hipMemsetAsync(cur1, 0, 64, stream);  // covers cur1 + cur2

  // ---- CSR build (bucketed counting sort) ----
  countA_k<<<NBLKA, 256, 0, stream>>>(dst, gbase);
  scanB_k<<<1, 256, 0, stream>>>(gbase, boff, cursor);
  scatterA_k<<<NBLKA, 256, 0, stream>>>(src, dst, cursor, tmp);
  csrC_k<<<NBUK, 512, 0, stream>>>(tmp, boff, rp, col);

  // ---- layer 1: x(f32) -> xl(buf1,sharded), xr(buf2,sharded); gather -> h1(buf3) ----
  transform_mfma_k<float><<<(NSTRIP + 3) / 4, 256, 0, stream>>>(x, W1l, W1r,
                                                                buf1, buf2);
  gather_k<0><<<2048, 256, 0, stream>>>((const uint_t*)buf1, (const uint_t*)buf2,
                                        b1l, rp, col, (uint_t*)buf3,
                                        nullptr, nullptr, nullptr, cur1);
  // ---- layer 2: h1(buf3,sharded) -> h2l(buf1), h2r(buf2); gather+pool ----
  transform_mfma_k<ushort_t><<<(NSTRIP + 3) / 4, 256, 0, stream>>>(buf3, W2l, W2r,
                                                                   buf1, buf2);
  gather_k<1><<<2048, 256, 0, stream>>>((const uint_t*)buf1, (const uint_t*)buf2,
                                        b2l, rp, col, nullptr,
                                        bat, gsum, gcnt, cur2);
  // ---- classify ----
  final_k<<<1, 256, 0, stream>>>(gsum, gcnt, Wc, bc, out);
}

// Round 12
// 211.341 us; speedup vs baseline: 2.8156x; 1.8931x over previous
//
#include <hip/hip_runtime.h>

#define N_NODES 100000
#define N_EDGES 1200000
#define CH 64
#define NG 256
#define OC 8
#define NBUK 196        // ceil(N_NODES/512)
#define BINCHUNK 4096
#define NBLKA 293       // ceil(N_EDGES/BINCHUNK)
#define NSTRIP 6250     // N_NODES/16 (exact)

typedef unsigned short ushort_t;
typedef unsigned int uint_t;
typedef __attribute__((ext_vector_type(8))) short bf16x8;
typedef __attribute__((ext_vector_type(4))) float f32x4;

__device__ __forceinline__ ushort_t f2bf(float f) {  // RNE f32->bf16
  uint_t u = __float_as_uint(f);
  return (ushort_t)((u + 0x7FFFu + ((u >> 16) & 1u)) >> 16);
}
__device__ __forceinline__ float bf2f(ushort_t b) {
  return __uint_as_float(((uint_t)b) << 16);
}

// ---------------- W -> bf16 prep (once per launch; kills per-wave re-convert) ----
__global__ void prep_k(const float* __restrict__ W1l, const float* __restrict__ W1r,
                       const float* __restrict__ W2l, const float* __restrict__ W2r,
                       ushort_t* __restrict__ wb) {
  const int i = threadIdx.x;  // 256 threads
  for (int k = i; k < CH * CH; k += 256) {
    wb[k]                = f2bf(W1l[k]);
    wb[k + CH * CH]      = f2bf(W1r[k]);
    wb[k + 2 * CH * CH]  = f2bf(W2l[k]);
    wb[k + 3 * CH * CH]  = f2bf(W2r[k]);
  }
}

// ---------------- pass A1: per-bucket totals (dst>>9) ----------------
__global__ __launch_bounds__(256) void countA_k(const int* __restrict__ dst,
                                                int* __restrict__ gbase) {
  __shared__ int hist[NBUK];
  for (int i = threadIdx.x; i < NBUK; i += 256) hist[i] = 0;
  __syncthreads();
  const int cs = blockIdx.x * BINCHUNK;
  int ce = cs + BINCHUNK;
  if (ce > N_EDGES) ce = N_EDGES;
  for (int e = cs + threadIdx.x; e < ce; e += 256)
    atomicAdd(&hist[dst[e] >> 9], 1);
  __syncthreads();
  for (int b = threadIdx.x; b < NBUK; b += 256) {
    int c = hist[b];
    if (c) atomicAdd(&gbase[b], c);
  }
}

// ---------------- pass B: exclusive scan -> boff; cursor = boff ----------------
__global__ void scanB_k(const int* __restrict__ gbase, int* __restrict__ boff,
                        int* __restrict__ cursor) {
  __shared__ int s[256];
  int v = (threadIdx.x < NBUK) ? gbase[threadIdx.x] : 0;
  s[threadIdx.x] = v;
  __syncthreads();
  for (int o = 1; o < 256; o <<= 1) {
    int t = (threadIdx.x >= o) ? s[threadIdx.x - o] : 0;
    __syncthreads();
    s[threadIdx.x] += t;
    __syncthreads();
  }
  if (threadIdx.x < NBUK) {
    int ex = s[threadIdx.x] - v;
    boff[threadIdx.x] = ex;
    cursor[threadIdx.x] = ex;
  }
  if (threadIdx.x == NBUK - 1) boff[NBUK] = s[threadIdx.x];
}

// ---------------- pass A2: scatter packed edges into bucket regions ----------------
__global__ __launch_bounds__(256) void scatterA_k(const int* __restrict__ src,
                                                  const int* __restrict__ dst,
                                                  int* __restrict__ cursor,
                                                  int* __restrict__ tmp) {
  __shared__ int hist[NBUK];
  for (int i = threadIdx.x; i < NBUK; i += 256) hist[i] = 0;
  __syncthreads();
  const int cs = blockIdx.x * BINCHUNK;
  int ce = cs + BINCHUNK;
  if (ce > N_EDGES) ce = N_EDGES;
  for (int e = cs + threadIdx.x; e < ce; e += 256)
    atomicAdd(&hist[dst[e] >> 9], 1);
  __syncthreads();
  for (int b = threadIdx.x; b < NBUK; b += 256) {
    int c = hist[b];
    hist[b] = c ? atomicAdd(&cursor[b], c) : 0;
  }
  __syncthreads();
  for (int e = cs + threadIdx.x; e < ce; e += 256) {
    int d = dst[e];
    int slot = atomicAdd(&hist[d >> 9], 1);
    tmp[slot] = (src[e] << 9) | (d & 511);
  }
}

// ---------------- pass C: per-bucket fine CSR (rowptr + col) ----------------
__global__ __launch_bounds__(512) void csrC_k(const int* __restrict__ tmp,
                                              const int* __restrict__ boff,
                                              int* __restrict__ rp,
                                              int* __restrict__ col) {
  __shared__ int lh[512];
  __shared__ int s[512];
  const int b = blockIdx.x;
  const int tid = threadIdx.x;
  const int eb = boff[b], ee = boff[b + 1];
  lh[tid] = 0;
  __syncthreads();
  for (int e = eb + tid; e < ee; e += 512) atomicAdd(&lh[tmp[e] & 511], 1);
  __syncthreads();
  int v = lh[tid];
  s[tid] = v;
  __syncthreads();
  for (int o = 1; o < 512; o <<= 1) {
    int t = (tid >= o) ? s[tid - o] : 0;
    __syncthreads();
    s[tid] += t;
    __syncthreads();
  }
  const int base = eb + s[tid] - v;
  const int node = b * 512 + tid;
  if (node < N_NODES) rp[node] = base;
  if (b == 0 && tid == 0) rp[N_NODES] = N_EDGES;
  lh[tid] = base;
  __syncthreads();
  for (int e = eb + tid; e < ee; e += 512) {
    int p = tmp[e];
    int slot = atomicAdd(&lh[p & 511], 1);
    col[slot] = p >> 9;
  }
}

// ---------------- MFMA dual transform: outl/outr (bf16) = in@Wl^T / in@Wr^T ----
// B-fragments load pre-converted bf16 weights directly (no per-wave f2bf).
// One wave per 16-node strip. TIN = float (layer 1) or ushort_t (layer 2).
// C/D mapping: col=lane&15, row=(lane>>4)*4+reg  [m89-verified].
template <typename TIN>
__global__ __launch_bounds__(256) void transform_mfma_k(
    const TIN* __restrict__ in, const ushort_t* __restrict__ Wlb,
    const ushort_t* __restrict__ Wrb, ushort_t* __restrict__ outl,
    ushort_t* __restrict__ outr) {
  const int wid = blockIdx.x * 4 + (threadIdx.x >> 6);
  if (wid >= NSTRIP) return;
  const int lane = threadIdx.x & 63;
  const int row = lane & 15;
  const int kb = lane >> 4;  // k-block 0..3 (8 contiguous k each)

  // B fragments: direct bf16x8 loads (16B each), tile t<4 -> Wl, t>=4 -> Wr
  bf16x8 Bfrag[8][2];
#pragma unroll
  for (int t = 0; t < 8; ++t) {
    const ushort_t* W = (t < 4) ? Wlb : Wrb;
    const int j = (t & 3) * 16 + row;  // output channel = W row
#pragma unroll
    for (int h = 0; h < 2; ++h)
      Bfrag[t][h] = *(const bf16x8*)(W + j * CH + h * 32 + kb * 8);
  }

  const int n0 = wid * 16;
  bf16x8 Afrag[2];
#pragma unroll
  for (int h = 0; h < 2; ++h) {
    if constexpr (sizeof(TIN) == 4) {
      const float* p = (const float*)in + (size_t)(n0 + row) * CH + h * 32 + kb * 8;
      float4 a0 = *(const float4*)p;
      float4 a1 = *(const float4*)(p + 4);
      bf16x8 a;
      a[0] = (short)f2bf(a0.x); a[1] = (short)f2bf(a0.y);
      a[2] = (short)f2bf(a0.z); a[3] = (short)f2bf(a0.w);
      a[4] = (short)f2bf(a1.x); a[5] = (short)f2bf(a1.y);
      a[6] = (short)f2bf(a1.z); a[7] = (short)f2bf(a1.w);
      Afrag[h] = a;
    } else {
      const ushort_t* p =
          (const ushort_t*)in + (size_t)(n0 + row) * CH + h * 32 + kb * 8;
      Afrag[h] = *(const bf16x8*)p;  // 16B-aligned direct bf16 load
    }
  }

  f32x4 acc[8];
#pragma unroll
  for (int t = 0; t < 8; ++t) {
    acc[t] = (f32x4){0.f, 0.f, 0.f, 0.f};
    acc[t] = __builtin_amdgcn_mfma_f32_16x16x32_bf16(Afrag[0], Bfrag[t][0],
                                                     acc[t], 0, 0, 0);
    acc[t] = __builtin_amdgcn_mfma_f32_16x16x32_bf16(Afrag[1], Bfrag[t][1],
                                                     acc[t], 0, 0, 0);
  }

  const int orow = (lane >> 4) * 4;
#pragma unroll
  for (int t = 0; t < 4; ++t)
#pragma unroll
    for (int i = 0; i < 4; ++i)
      outl[(size_t)(n0 + orow + i) * CH + t * 16 + row] = f2bf(acc[t][i]);
#pragma unroll
  for (int t = 4; t < 8; ++t)
#pragma unroll
    for (int i = 0; i < 4; ++i)
      outr[(size_t)(n0 + orow + i) * CH + (t - 4) * 16 + row] = f2bf(acc[t][i]);
}

// ---------------- gather(bf16) + mean + bias + relu (+ optional pool) ----------------
// lane = channel; gl, gr, outh all bf16 row-major [N][64].
template <int MODE>
__global__ __launch_bounds__(256) void gather_k(
    const ushort_t* __restrict__ gl, const ushort_t* __restrict__ gr,
    const float* __restrict__ bl, const int* __restrict__ rowptr,
    const int* __restrict__ col, ushort_t* __restrict__ outh,
    const int* __restrict__ batch, float* __restrict__ gsum,
    int* __restrict__ gcnt) {
  const int lane = threadIdx.x & 63;
  const float biasv = bl[lane];
  const int wid = blockIdx.x * (blockDim.x >> 6) + (threadIdx.x >> 6);
  const int nw = gridDim.x * (blockDim.x >> 6);
  const int per = (N_NODES + nw - 1) / nw;
  int ns = wid * per;
  int ne = ns + per;
  if (ne > N_NODES) ne = N_NODES;
  if (ns >= ne) return;

  int curg = -1;
  float paccv = 0.f;
  int pcnt = 0;

  for (int n = ns; n < ne; ++n) {
    const int eb = rowptr[n], ee = rowptr[n + 1];
    float a0 = 0.f, a1 = 0.f, a2 = 0.f, a3 = 0.f;
    float a4 = 0.f, a5 = 0.f, a6 = 0.f, a7 = 0.f;
    int i = eb;
    for (; i + 8 <= ee; i += 8) {
      int c0 = col[i],     c1 = col[i + 1], c2 = col[i + 2], c3 = col[i + 3];
      int c4 = col[i + 4], c5 = col[i + 5], c6 = col[i + 6], c7 = col[i + 7];
      a0 += bf2f(gl[(size_t)c0 * CH + lane]);
      a1 += bf2f(gl[(size_t)c1 * CH + lane]);
      a2 += bf2f(gl[(size_t)c2 * CH + lane]);
      a3 += bf2f(gl[(size_t)c3 * CH + lane]);
      a4 += bf2f(gl[(size_t)c4 * CH + lane]);
      a5 += bf2f(gl[(size_t)c5 * CH + lane]);
      a6 += bf2f(gl[(size_t)c6 * CH + lane]);
      a7 += bf2f(gl[(size_t)c7 * CH + lane]);
    }
    for (; i + 4 <= ee; i += 4) {
      int c0 = col[i], c1 = col[i + 1], c2 = col[i + 2], c3 = col[i + 3];
      a0 += bf2f(gl[(size_t)c0 * CH + lane]);
      a1 += bf2f(gl[(size_t)c1 * CH + lane]);
      a2 += bf2f(gl[(size_t)c2 * CH + lane]);
      a3 += bf2f(gl[(size_t)c3 * CH + lane]);
    }
    for (; i < ee; ++i) a0 += bf2f(gl[(size_t)col[i] * CH + lane]);
    const int deg = ee - eb;
    const float inv = deg > 0 ? 1.f / (float)deg : 1.f;
    const float s = ((a0 + a1) + (a2 + a3)) + ((a4 + a5) + (a6 + a7));
    const float r =
        fmaxf(fmaf(s, inv, biasv + bf2f(gr[(size_t)n * CH + lane])), 0.f);
    if (MODE == 0) {
      outh[(size_t)n * CH + lane] = f2bf(r);
    } else {
      int g = batch[n];
      if (g != curg) {
        if (curg >= 0) {
          atomicAdd(&gsum[curg * CH + lane], paccv);
          if (lane == 0) atomicAdd(&gcnt[curg], pcnt);
        }
        curg = g;
        paccv = 0.f;
        pcnt = 0;
      }
      paccv += r;
      pcnt++;
    }
  }
  if (MODE == 1 && curg >= 0) {
    atomicAdd(&gsum[curg * CH + lane], paccv);
    if (lane == 0) atomicAdd(&gcnt[curg], pcnt);
  }
}

// ---------------- final projection ----------------
__global__ void final_k(const float* __restrict__ gsum, const int* __restrict__ gcnt,
                        const float* __restrict__ Wc, const float* __restrict__ bc,
                        float* __restrict__ out) {
  __shared__ float Wcs[OC * CH];
  __shared__ float bcs[OC];
  for (int i = threadIdx.x; i < OC * CH; i += blockDim.x) Wcs[i] = Wc[i];
  if (threadIdx.x < OC) bcs[threadIdx.x] = bc[threadIdx.x];
  __syncthreads();
  int g = threadIdx.x;
  float c = (float)gcnt[g];
  float inv = c > 0.f ? 1.f / c : 1.f;
  float gr[CH];
#pragma unroll
  for (int k = 0; k < CH; ++k) gr[k] = gsum[g * CH + k] * inv;
#pragma unroll
  for (int o = 0; o < OC; ++o) {
    float acc = bcs[o];
#pragma unroll
    for (int k = 0; k < CH; ++k) acc += gr[k] * Wcs[o * CH + k];
    out[g * OC + o] = acc;
  }
}

extern "C" void kernel_launch(void* const* d_in, const int* in_sizes, int n_in,
                              void* d_out, int out_size, void* d_ws, size_t ws_size,
                              hipStream_t stream) {
  const float* x   = (const float*)d_in[0];
  const int*   ei  = (const int*)d_in[1];
  const int*   bat = (const int*)d_in[2];
  const float* W1l = (const float*)d_in[3];
  const float* b1l = (const float*)d_in[4];
  const float* W1r = (const float*)d_in[5];
  const float* W2l = (const float*)d_in[6];
  const float* b2l = (const float*)d_in[7];
  const float* W2r = (const float*)d_in[8];
  const float* Wc  = (const float*)d_in[9];
  const float* bc  = (const float*)d_in[10];
  float* out = (float*)d_out;

  char* ws = (char*)d_ws;
  // row-major bf16 node buffers (12.8MB each):
  //   buf1: xl -> h2l     buf3: h1     buf2: xr -> h2r
  ushort_t* buf1 = (ushort_t*)(ws + 0);         // 12,800,000 B
  ushort_t* buf3 = (ushort_t*)(ws + 12800000);  // 12,800,000 B
  ushort_t* buf2 = (ushort_t*)(ws + 25600000);  // 12,800,000 B
  int*   tmp     = (int*)(ws + 0);              //  4,800,000 B (aliased w/ buf1; CSR phase only)
  int*   rp      = (int*)(ws + 51200000);       //    400,128 B (incl pad)
  int*   col     = (int*)(ws + 51600128);       //  4,800,000 B
  int*   gbase   = (int*)(ws + 56400128);       //      1,024 B
  int*   boff    = (int*)(ws + 56401152);       //      1,024 B
  int*   cursor  = (int*)(ws + 56402176);       //      1,024 B
  float* gsum    = (float*)(ws + 56403200);     //     65,536 B
  int*   gcnt    = (int*)(ws + 56468736);       //      1,024 B
  ushort_t* wbf  = (ushort_t*)(ws + 56469760);  //     32,768 B (4x 64x64 bf16)

  const int* src = ei;
  const int* dst = ei + N_EDGES;

  hipMemsetAsync(gbase, 0, NBUK * sizeof(int), stream);
  hipMemsetAsync(gsum, 0, (size_t)NG * CH * sizeof(float) + NG * sizeof(int), stream);

  // ---- weight prep + CSR build ----
  prep_k<<<1, 256, 0, stream>>>(W1l, W1r, W2l, W2r, wbf);
  countA_k<<<NBLKA, 256, 0, stream>>>(dst, gbase);
  scanB_k<<<1, 256, 0, stream>>>(gbase, boff, cursor);
  scatterA_k<<<NBLKA, 256, 0, stream>>>(src, dst, cursor, tmp);
  csrC_k<<<NBUK, 512, 0, stream>>>(tmp, boff, rp, col);

  // ---- layer 1: x(f32) -> xl(buf1), xr(buf2); gather -> h1(buf3) ----
  transform_mfma_k<float><<<(NSTRIP + 3) / 4, 256, 0, stream>>>(
      x, wbf, wbf + CH * CH, buf1, buf2);
  gather_k<0><<<2048, 256, 0, stream>>>(buf1, buf2, b1l, rp, col, buf3,
                                        nullptr, nullptr, nullptr);
  // ---- layer 2: h1(buf3) -> h2l(buf1), h2r(buf2); gather+pool ----
  transform_mfma_k<ushort_t><<<(NSTRIP + 3) / 4, 256, 0, stream>>>(
      buf3, wbf + 2 * CH * CH, wbf + 3 * CH * CH, buf1, buf2);
  gather_k<1><<<2048, 256, 0, stream>>>(buf1, buf2, b2l, rp, col, nullptr,
                                        bat, gsum, gcnt);
  // ---- classify ----
  final_k<<<1, 256, 0, stream>>>(gsum, gcnt, Wc, bc, out);
}

// Round 13
// 204.387 us; speedup vs baseline: 2.9114x; 1.0340x over previous
//
#include <hip/hip_runtime.h>

#define N_NODES 100000
#define N_EDGES 1200000
#define CH 64
#define NG 256
#define OC 8
#define NBUK 196        // ceil(N_NODES/512)
#define BINCHUNK 4096
#define NBLKA 293       // ceil(N_EDGES/BINCHUNK)
#define NSTRIP 6250     // N_NODES/16 (exact)
#define ZERO_U4 4224    // (65536+1024+1024)/16 : gsum+gcnt+gbase

typedef unsigned short ushort_t;
typedef unsigned int uint_t;
typedef __attribute__((ext_vector_type(8))) short bf16x8;
typedef __attribute__((ext_vector_type(4))) float f32x4;

__device__ __forceinline__ ushort_t f2bf(float f) {  // RNE f32->bf16
  uint_t u = __float_as_uint(f);
  return (ushort_t)((u + 0x7FFFu + ((u >> 16) & 1u)) >> 16);
}
__device__ __forceinline__ float bf2f(ushort_t b) {
  return __uint_as_float(((uint_t)b) << 16);
}

// ---------------- prep: W -> bf16 + zero accumulators (replaces 3 memsets) ----
__global__ void prep_k(const float* __restrict__ W1l, const float* __restrict__ W1r,
                       const float* __restrict__ W2l, const float* __restrict__ W2r,
                       ushort_t* __restrict__ wb, uint4* __restrict__ zr) {
  const int gi = blockIdx.x * blockDim.x + threadIdx.x;
  for (int i = gi; i < ZERO_U4; i += gridDim.x * blockDim.x)
    zr[i] = make_uint4(0, 0, 0, 0);
  if (blockIdx.x == 0) {
    for (int k = threadIdx.x; k < CH * CH; k += 256) {
      wb[k]               = f2bf(W1l[k]);
      wb[k + CH * CH]     = f2bf(W1r[k]);
      wb[k + 2 * CH * CH] = f2bf(W2l[k]);
      wb[k + 3 * CH * CH] = f2bf(W2r[k]);
    }
  }
}

// ---------------- pass A1: per-bucket totals (dst>>9) ----------------
__global__ __launch_bounds__(256) void countA_k(const int* __restrict__ dst,
                                                int* __restrict__ gbase) {
  __shared__ int hist[NBUK];
  for (int i = threadIdx.x; i < NBUK; i += 256) hist[i] = 0;
  __syncthreads();
  const int cs = blockIdx.x * BINCHUNK;
  int ce = cs + BINCHUNK;
  if (ce > N_EDGES) ce = N_EDGES;
  for (int e = cs + threadIdx.x; e < ce; e += 256)
    atomicAdd(&hist[dst[e] >> 9], 1);
  __syncthreads();
  for (int b = threadIdx.x; b < NBUK; b += 256) {
    int c = hist[b];
    if (c) atomicAdd(&gbase[b], c);
  }
}

// ---------------- pass B: exclusive scan -> boff; cursor = boff ----------------
__global__ void scanB_k(const int* __restrict__ gbase, int* __restrict__ boff,
                        int* __restrict__ cursor) {
  __shared__ int s[256];
  int v = (threadIdx.x < NBUK) ? gbase[threadIdx.x] : 0;
  s[threadIdx.x] = v;
  __syncthreads();
  for (int o = 1; o < 256; o <<= 1) {
    int t = (threadIdx.x >= o) ? s[threadIdx.x - o] : 0;
    __syncthreads();
    s[threadIdx.x] += t;
    __syncthreads();
  }
  if (threadIdx.x < NBUK) {
    int ex = s[threadIdx.x] - v;
    boff[threadIdx.x] = ex;
    cursor[threadIdx.x] = ex;
  }
  if (threadIdx.x == NBUK - 1) boff[NBUK] = s[threadIdx.x];
}

// ---------------- pass A2: scatter packed edges into bucket regions ----------------
__global__ __launch_bounds__(256) void scatterA_k(const int* __restrict__ src,
                                                  const int* __restrict__ dst,
                                                  int* __restrict__ cursor,
                                                  int* __restrict__ tmp) {
  __shared__ int hist[NBUK];
  for (int i = threadIdx.x; i < NBUK; i += 256) hist[i] = 0;
  __syncthreads();
  const int cs = blockIdx.x * BINCHUNK;
  int ce = cs + BINCHUNK;
  if (ce > N_EDGES) ce = N_EDGES;
  for (int e = cs + threadIdx.x; e < ce; e += 256)
    atomicAdd(&hist[dst[e] >> 9], 1);
  __syncthreads();
  for (int b = threadIdx.x; b < NBUK; b += 256) {
    int c = hist[b];
    hist[b] = c ? atomicAdd(&cursor[b], c) : 0;
  }
  __syncthreads();
  for (int e = cs + threadIdx.x; e < ce; e += 256) {
    int d = dst[e];
    int slot = atomicAdd(&hist[d >> 9], 1);
    tmp[slot] = (src[e] << 9) | (d & 511);
  }
}

// ---------------- pass C: per-bucket fine CSR (rowptr + col) ----------------
// col stores src*CH (pre-scaled row offset) to save a VALU op in the gather.
__global__ __launch_bounds__(512) void csrC_k(const int* __restrict__ tmp,
                                              const int* __restrict__ boff,
                                              int* __restrict__ rp,
                                              int* __restrict__ col) {
  __shared__ int lh[512];
  __shared__ int s[512];
  const int b = blockIdx.x;
  const int tid = threadIdx.x;
  const int eb = boff[b], ee = boff[b + 1];
  lh[tid] = 0;
  __syncthreads();
  for (int e = eb + tid; e < ee; e += 512) atomicAdd(&lh[tmp[e] & 511], 1);
  __syncthreads();
  int v = lh[tid];
  s[tid] = v;
  __syncthreads();
  for (int o = 1; o < 512; o <<= 1) {
    int t = (tid >= o) ? s[tid - o] : 0;
    __syncthreads();
    s[tid] += t;
    __syncthreads();
  }
  const int base = eb + s[tid] - v;
  const int node = b * 512 + tid;
  if (node < N_NODES) rp[node] = base;
  if (b == 0 && tid == 0) rp[N_NODES] = N_EDGES;
  lh[tid] = base;
  __syncthreads();
  for (int e = eb + tid; e < ee; e += 512) {
    int p = tmp[e];
    int slot = atomicAdd(&lh[p & 511], 1);
    col[slot] = (p >> 9) * CH;
  }
}

// ---------------- MFMA dual transform: outl/outr (bf16) = in@Wl^T / in@Wr^T ----
// B-fragments load pre-converted bf16 weights directly (no per-wave f2bf).
// One wave per 16-node strip. TIN = float (layer 1) or ushort_t (layer 2).
// C/D mapping: col=lane&15, row=(lane>>4)*4+reg  [m89-verified].
template <typename TIN>
__global__ __launch_bounds__(256) void transform_mfma_k(
    const TIN* __restrict__ in, const ushort_t* __restrict__ Wlb,
    const ushort_t* __restrict__ Wrb, ushort_t* __restrict__ outl,
    ushort_t* __restrict__ outr) {
  const int wid = blockIdx.x * 4 + (threadIdx.x >> 6);
  if (wid >= NSTRIP) return;
  const int lane = threadIdx.x & 63;
  const int row = lane & 15;
  const int kb = lane >> 4;  // k-block 0..3 (8 contiguous k each)

  // B fragments: direct bf16x8 loads (16B each), tile t<4 -> Wl, t>=4 -> Wr
  bf16x8 Bfrag[8][2];
#pragma unroll
  for (int t = 0; t < 8; ++t) {
    const ushort_t* W = (t < 4) ? Wlb : Wrb;
    const int j = (t & 3) * 16 + row;  // output channel = W row
#pragma unroll
    for (int h = 0; h < 2; ++h)
      Bfrag[t][h] = *(const bf16x8*)(W + j * CH + h * 32 + kb * 8);
  }

  const int n0 = wid * 16;
  bf16x8 Afrag[2];
#pragma unroll
  for (int h = 0; h < 2; ++h) {
    if constexpr (sizeof(TIN) == 4) {
      const float* p = (const float*)in + (size_t)(n0 + row) * CH + h * 32 + kb * 8;
      float4 a0 = *(const float4*)p;
      float4 a1 = *(const float4*)(p + 4);
      bf16x8 a;
      a[0] = (short)f2bf(a0.x); a[1] = (short)f2bf(a0.y);
      a[2] = (short)f2bf(a0.z); a[3] = (short)f2bf(a0.w);
      a[4] = (short)f2bf(a1.x); a[5] = (short)f2bf(a1.y);
      a[6] = (short)f2bf(a1.z); a[7] = (short)f2bf(a1.w);
      Afrag[h] = a;
    } else {
      const ushort_t* p =
          (const ushort_t*)in + (size_t)(n0 + row) * CH + h * 32 + kb * 8;
      Afrag[h] = *(const bf16x8*)p;  // 16B-aligned direct bf16 load
    }
  }

  f32x4 acc[8];
#pragma unroll
  for (int t = 0; t < 8; ++t) {
    acc[t] = (f32x4){0.f, 0.f, 0.f, 0.f};
    acc[t] = __builtin_amdgcn_mfma_f32_16x16x32_bf16(Afrag[0], Bfrag[t][0],
                                                     acc[t], 0, 0, 0);
    acc[t] = __builtin_amdgcn_mfma_f32_16x16x32_bf16(Afrag[1], Bfrag[t][1],
                                                     acc[t], 0, 0, 0);
  }

  const int orow = (lane >> 4) * 4;
#pragma unroll
  for (int t = 0; t < 4; ++t)
#pragma unroll
    for (int i = 0; i < 4; ++i)
      outl[(size_t)(n0 + orow + i) * CH + t * 16 + row] = f2bf(acc[t][i]);
#pragma unroll
  for (int t = 4; t < 8; ++t)
#pragma unroll
    for (int i = 0; i < 4; ++i)
      outr[(size_t)(n0 + orow + i) * CH + (t - 4) * 16 + row] = f2bf(acc[t][i]);
}

// ---------------- gather(bf16) + mean + bias + relu (+ optional pool) ----------------
// lane = channel; gl random reads stay CACHED; gr loads and outh stores are
// NON-TEMPORAL so the streaming traffic stops evicting gl from L2.
template <int MODE>
__global__ __launch_bounds__(256) void gather_k(
    const ushort_t* __restrict__ gl, const ushort_t* __restrict__ gr,
    const float* __restrict__ bl, const int* __restrict__ rowptr,
    const int* __restrict__ col, ushort_t* __restrict__ outh,
    const int* __restrict__ batch, float* __restrict__ gsum,
    int* __restrict__ gcnt) {
  const int lane = threadIdx.x & 63;
  const float biasv = bl[lane];
  const int wid = blockIdx.x * (blockDim.x >> 6) + (threadIdx.x >> 6);
  const int nw = gridDim.x * (blockDim.x >> 6);
  const int per = (N_NODES + nw - 1) / nw;
  int ns = wid * per;
  int ne = ns + per;
  if (ne > N_NODES) ne = N_NODES;
  if (ns >= ne) return;

  int curg = -1;
  float paccv = 0.f;
  int pcnt = 0;

  for (int n = ns; n < ne; ++n) {
    const int eb = rowptr[n], ee = rowptr[n + 1];
    float a0 = 0.f, a1 = 0.f, a2 = 0.f, a3 = 0.f;
    float a4 = 0.f, a5 = 0.f, a6 = 0.f, a7 = 0.f;
    int i = eb;
    for (; i + 8 <= ee; i += 8) {
      int c0 = col[i],     c1 = col[i + 1], c2 = col[i + 2], c3 = col[i + 3];
      int c4 = col[i + 4], c5 = col[i + 5], c6 = col[i + 6], c7 = col[i + 7];
      a0 += bf2f(gl[(size_t)c0 + lane]);
      a1 += bf2f(gl[(size_t)c1 + lane]);
      a2 += bf2f(gl[(size_t)c2 + lane]);
      a3 += bf2f(gl[(size_t)c3 + lane]);
      a4 += bf2f(gl[(size_t)c4 + lane]);
      a5 += bf2f(gl[(size_t)c5 + lane]);
      a6 += bf2f(gl[(size_t)c6 + lane]);
      a7 += bf2f(gl[(size_t)c7 + lane]);
    }
    for (; i + 4 <= ee; i += 4) {
      int c0 = col[i], c1 = col[i + 1], c2 = col[i + 2], c3 = col[i + 3];
      a0 += bf2f(gl[(size_t)c0 + lane]);
      a1 += bf2f(gl[(size_t)c1 + lane]);
      a2 += bf2f(gl[(size_t)c2 + lane]);
      a3 += bf2f(gl[(size_t)c3 + lane]);
    }
    for (; i < ee; ++i) a0 += bf2f(gl[(size_t)col[i] + lane]);
    const int deg = ee - eb;
    const float inv = deg > 0 ? 1.f / (float)deg : 1.f;
    const float s = ((a0 + a1) + (a2 + a3)) + ((a4 + a5) + (a6 + a7));
    const ushort_t gv = __builtin_nontemporal_load(&gr[(size_t)n * CH + lane]);
    const float r = fmaxf(fmaf(s, inv, biasv + bf2f(gv)), 0.f);
    if (MODE == 0) {
      __builtin_nontemporal_store(f2bf(r), &outh[(size_t)n * CH + lane]);
    } else {
      int g = batch[n];
      if (g != curg) {
        if (curg >= 0) {
          atomicAdd(&gsum[curg * CH + lane], paccv);
          if (lane == 0) atomicAdd(&gcnt[curg], pcnt);
        }
        curg = g;
        paccv = 0.f;
        pcnt = 0;
      }
      paccv += r;
      pcnt++;
    }
  }
  if (MODE == 1 && curg >= 0) {
    atomicAdd(&gsum[curg * CH + lane], paccv);
    if (lane == 0) atomicAdd(&gcnt[curg], pcnt);
  }
}

// ---------------- final projection ----------------
__global__ void final_k(const float* __restrict__ gsum, const int* __restrict__ gcnt,
                        const float* __restrict__ Wc, const float* __restrict__ bc,
                        float* __restrict__ out) {
  __shared__ float Wcs[OC * CH];
  __shared__ float bcs[OC];
  for (int i = threadIdx.x; i < OC * CH; i += blockDim.x) Wcs[i] = Wc[i];
  if (threadIdx.x < OC) bcs[threadIdx.x] = bc[threadIdx.x];
  __syncthreads();
  int g = threadIdx.x;
  float c = (float)gcnt[g];
  float inv = c > 0.f ? 1.f / c : 1.f;
  float gr[CH];
#pragma unroll
  for (int k = 0; k < CH; ++k) gr[k] = gsum[g * CH + k] * inv;
#pragma unroll
  for (int o = 0; o < OC; ++o) {
    float acc = bcs[o];
#pragma unroll
    for (int k = 0; k < CH; ++k) acc += gr[k] * Wcs[o * CH + k];
    out[g * OC + o] = acc;
  }
}

extern "C" void kernel_launch(void* const* d_in, const int* in_sizes, int n_in,
                              void* d_out, int out_size, void* d_ws, size_t ws_size,
                              hipStream_t stream) {
  const float* x   = (const float*)d_in[0];
  const int*   ei  = (const int*)d_in[1];
  const int*   bat = (const int*)d_in[2];
  const float* W1l = (const float*)d_in[3];
  const float* b1l = (const float*)d_in[4];
  const float* W1r = (const float*)d_in[5];
  const float* W2l = (const float*)d_in[6];
  const float* b2l = (const float*)d_in[7];
  const float* W2r = (const float*)d_in[8];
  const float* Wc  = (const float*)d_in[9];
  const float* bc  = (const float*)d_in[10];
  float* out = (float*)d_out;

  char* ws = (char*)d_ws;
  // row-major bf16 node buffers (12.8MB each):
  //   buf1: xl -> h2l     buf3: h1     buf2: xr -> h2r
  ushort_t* buf1 = (ushort_t*)(ws + 0);         // 12,800,000 B
  ushort_t* buf3 = (ushort_t*)(ws + 12800000);  // 12,800,000 B
  ushort_t* buf2 = (ushort_t*)(ws + 25600000);  // 12,800,000 B
  int*   tmp     = (int*)(ws + 0);              //  4,800,000 B (aliased w/ buf1; CSR phase only)
  int*   rp      = (int*)(ws + 51200000);       //    400,128 B (incl pad)
  int*   col     = (int*)(ws + 51600128);       //  4,800,000 B
  // contiguous zero region: gsum + gcnt + gbase (67,584 B)
  float* gsum    = (float*)(ws + 56400128);     //     65,536 B
  int*   gcnt    = (int*)(ws + 56465664);       //      1,024 B
  int*   gbase   = (int*)(ws + 56466688);       //      1,024 B
  int*   boff    = (int*)(ws + 56467712);       //      1,024 B
  int*   cursor  = (int*)(ws + 56468736);       //      1,024 B
  ushort_t* wbf  = (ushort_t*)(ws + 56469760);  //     32,768 B (4x 64x64 bf16)

  const int* src = ei;
  const int* dst = ei + N_EDGES;

  // ---- prep (W->bf16 + zero gsum/gcnt/gbase) + CSR build ----
  prep_k<<<32, 256, 0, stream>>>(W1l, W1r, W2l, W2r, wbf,
                                 (uint4*)(ws + 56400128));
  countA_k<<<NBLKA, 256, 0, stream>>>(dst, gbase);
  scanB_k<<<1, 256, 0, stream>>>(gbase, boff, cursor);
  scatterA_k<<<NBLKA, 256, 0, stream>>>(src, dst, cursor, tmp);
  csrC_k<<<NBUK, 512, 0, stream>>>(tmp, boff, rp, col);

  // ---- layer 1: x(f32) -> xl(buf1), xr(buf2); gather -> h1(buf3) ----
  transform_mfma_k<float><<<(NSTRIP + 3) / 4, 256, 0, stream>>>(
      x, wbf, wbf + CH * CH, buf1, buf2);
  gather_k<0><<<2048, 256, 0, stream>>>(buf1, buf2, b1l, rp, col, buf3,
                                        nullptr, nullptr, nullptr);
  // ---- layer 2: h1(buf3) -> h2l(buf1), h2r(buf2); gather+pool ----
  transform_mfma_k<ushort_t><<<(NSTRIP + 3) / 4, 256, 0, stream>>>(
      buf3, wbf + 2 * CH * CH, wbf + 3 * CH * CH, buf1, buf2);
  gather_k<1><<<2048, 256, 0, stream>>>(buf1, buf2, b2l, rp, col, nullptr,
                                        bat, gsum, gcnt);
  // ---- classify ----
  final_k<<<1, 256, 0, stream>>>(gsum, gcnt, Wc, bc, out);
}